// Round 7
// baseline (278.180 us; speedup 1.0000x reference)
//
#include <hip/hip_runtime.h>
#include <hip/hip_bf16.h>

typedef __attribute__((ext_vector_type(8))) short short8;   // 8 bf16 = 16B
typedef __attribute__((ext_vector_type(4))) short short4v;  // 4 bf16 = 8B
typedef __attribute__((ext_vector_type(4))) float f32x4;

#define GAS(p) ((const __attribute__((address_space(1))) void*)(p))
#define LAS(p) ((__attribute__((address_space(3))) void*)(p))

__device__ __forceinline__ short f2bf_bits(float f) {
    __hip_bfloat16 h = __float2bfloat16(f);
    return *reinterpret_cast<short*>(&h);
}

// ---------------- fp32 -> bf16 conversion, all three tensors in one launch --
__global__ __launch_bounds__(256) void cvt_all(const float* __restrict__ x,
                                               const float* __restrict__ w1,
                                               const float* __restrict__ w2,
                                               short* __restrict__ dx,
                                               short* __restrict__ dw1,
                                               short* __restrict__ dw2) {
    constexpr int N1 = 4194304, N2 = 3145728;   // x, w_in; w_out = 1048576
    int i = (blockIdx.x * 256 + threadIdx.x) * 8;
    const float* src; short* dst; int j;
    if (i < N1)            { src = x;  dst = dx;  j = i; }
    else if (i < N1 + N2)  { src = w1; dst = dw1; j = i - N1; }
    else                   { src = w2; dst = dw2; j = i - N1 - N2; }
    float4 a = *reinterpret_cast<const float4*>(src + j);
    float4 b = *reinterpret_cast<const float4*>(src + j + 4);
    short8 o;
    o[0] = f2bf_bits(a.x); o[1] = f2bf_bits(a.y);
    o[2] = f2bf_bits(a.z); o[3] = f2bf_bits(a.w);
    o[4] = f2bf_bits(b.x); o[5] = f2bf_bits(b.y);
    o[6] = f2bf_bits(b.z); o[7] = f2bf_bits(b.w);
    *reinterpret_cast<short8*>(dst + j) = o;
}

// ---------------- QKV projection GEMM ----------------
// 1D grid 768, XCD-chunked. V written directly transposed ([bh][d][L]) with
// packed 8B stores (4 consecutive l per store).
__global__ __launch_bounds__(256) void gemm_qkv(const __hip_bfloat16* __restrict__ A,
                                                const __hip_bfloat16* __restrict__ B,
                                                const float* __restrict__ bias,
                                                __hip_bfloat16* __restrict__ Qb,
                                                __hip_bfloat16* __restrict__ Kb,
                                                __hip_bfloat16* __restrict__ Vt) {
    constexpr int K = 1024;
    __shared__ __hip_bfloat16 smem[2][128 * 32 + 128 * 32];
    const int tid = threadIdx.x;
    const int lane = tid & 63, wid = tid >> 6;
    const int wr = wid >> 1, wc = wid & 1;
    const int lr = lane & 15, lg = lane >> 4;

    const int bid = blockIdx.x;
    const int xcd = bid & 7, w = bid >> 3;         // w in [0,96)
    const int bx = (xcd & 1) * 12 + (w % 12);      // [0,24)
    const int by = (xcd >> 1) * 8 + (w / 12);      // [0,32)
    const int m0 = by * 128;
    const int n0 = bx * 128;

    const f32x4 fz = {0.f, 0.f, 0.f, 0.f};
    f32x4 acc[4][4];
#pragma unroll
    for (int i = 0; i < 4; i++)
#pragma unroll
        for (int j = 0; j < 4; j++) acc[i][j] = fz;

    const char* Abase = (const char*)A + (size_t)m0 * K * 2;
    const char* Bbase = (const char*)B + (size_t)n0 * K * 2;

    auto stage = [&](int buf, int kt) {
        const int kb = kt * 64;
        char* sA = (char*)&smem[buf][0];
        char* sB = (char*)&smem[buf][128 * 32];
#pragma unroll
        for (int i = 0; i < 2; i++) {
            int o = i * 4096 + tid * 16;
            int row = o >> 6, cb = o & 63;
            __builtin_amdgcn_global_load_lds(GAS(Abase + (size_t)row * 2048 + kb + cb),
                                             LAS(sA + o), 16, 0, 0);
        }
#pragma unroll
        for (int i = 0; i < 2; i++) {
            int o = i * 4096 + tid * 16;
            int row = o >> 6, cb = o & 63;
            __builtin_amdgcn_global_load_lds(GAS(Bbase + (size_t)row * 2048 + kb + cb),
                                             LAS(sB + o), 16, 0, 0);
        }
    };

    stage(0, 0);
    __syncthreads();
    int buf = 0;
    constexpr int NT = K / 32;
    for (int kt = 0; kt < NT; ++kt) {
        if (kt + 1 < NT) stage(buf ^ 1, kt + 1);
        const __hip_bfloat16* sA = &smem[buf][0];
        const __hip_bfloat16* sB = &smem[buf][128 * 32];
        short8 a[4], b[4];
#pragma unroll
        for (int i = 0; i < 4; i++)
            a[i] = *reinterpret_cast<const short8*>(sA + (wr * 64 + i * 16 + lr) * 32 + lg * 8);
#pragma unroll
        for (int j = 0; j < 4; j++)
            b[j] = *reinterpret_cast<const short8*>(sB + (wc * 64 + j * 16 + lr) * 32 + lg * 8);
#pragma unroll
        for (int i = 0; i < 4; i++)
#pragma unroll
            for (int j = 0; j < 4; j++)
                acc[i][j] = __builtin_amdgcn_mfma_f32_16x16x32_bf16(a[i], b[j], acc[i][j], 0, 0, 0);
        __syncthreads();
        buf ^= 1;
    }

#pragma unroll
    for (int j = 0; j < 4; j++) {
        int e = n0 + wc * 64 + j * 16 + lr;
        float bv = bias[e];
        int sec = e >> 10;          // block-uniform (128-tiles never straddle)
        int el = e & 1023;
        int h = el >> 6, d = el & 63;
        // Q carries 1/sqrt(64) * log2(e) so attention can use exp2 directly
        float scale = (sec == 0) ? 0.18033688011112042f : 1.0f;
#pragma unroll
        for (int i = 0; i < 4; i++) {
            int mb = m0 + wr * 64 + i * 16 + lg * 4;
            if (sec == 2) {
                int bb = mb >> 11, l = mb & 2047;   // mb%4==0 -> no straddle
                short4v pv4;
#pragma unroll
                for (int r = 0; r < 4; r++) pv4[r] = f2bf_bits(acc[i][j][r] + bv);
                *reinterpret_cast<short4v*>(&Vt[((size_t)(bb * 16 + h) * 64 + d) * 2048 + l]) = pv4;
            } else {
#pragma unroll
                for (int r = 0; r < 4; r++) {
                    int tok = mb + r;
                    int bb = tok >> 11, l = tok & 2047;
                    float v = (acc[i][j][r] + bv) * scale;
                    __hip_bfloat16 hv = __float2bfloat16(v);
                    int bh = bb * 16 + h;
                    if (sec == 0) Qb[((size_t)bh * 2048 + l) * 64 + d] = hv;
                    else          Kb[((size_t)bh * 2048 + l) * 64 + d] = hv;
                }
            }
        }
    }
}

// ---------------- causal flash attention (barrier-free) ----------------
// 1024 blocks x 4 INDEPENDENT waves (no __syncthreads anywhere). K/V fragments
// are loaded directly from global (L2-resident: XCD pinning keeps each bh's
// K+V+Q ~3MB inside one XCD's 4MB L2). Only LDS use: private 2KB/wave P
// round-trip, ordered by lgkmcnt. Swapped QK^T, exp2 softmax, defer-max,
// lane-local lsum, setprio on MFMA. qt descending (long blocks first).
__global__ __launch_bounds__(256) void attn(const __hip_bfloat16* __restrict__ Qg,
                                            const __hip_bfloat16* __restrict__ Kg,
                                            const __hip_bfloat16* __restrict__ Vtg,
                                            __hip_bfloat16* __restrict__ ctx) {
    const int bid = blockIdx.x;
    const int xcd = bid & 7, seq = bid >> 3;       // seq in [0,128)
    const int bh = (xcd << 2) | (seq & 3);         // 4 bh per XCD
    const int qt = 31 - (seq >> 2);                // descending q-tiles
    const int tid = threadIdx.x, lane = tid & 63, wq = tid >> 6;
    const int lr = lane & 15, lg = lane >> 4;

    __shared__ short Ps[4][16 * 64];               // per-wave P, XOR-swizzled

    const int bb = bh >> 4, h = bh & 15;
    const int qb = qt * 64 + wq * 16;

    // per-lane global fragment bases
    // K frag (A-op): K[kv = kt*64 + n*16 + lr][d = lg*8..] -> row 128B
    const char* kL = (const char*)Kg + (size_t)bh * (2048 * 128) + lr * 128 + lg * 16;
    // V frag (B-op): Vt[d = n*16 + lr][kv = kt*64 + lg*8..] -> row 4096B
    const char* vL = (const char*)Vtg + (size_t)bh * (64 * 4096) + (size_t)lr * 4096 + lg * 16;

    // P LDS offsets (XOR swizzle on 8B granules within 128B rows)
    const int sw = (lr & 7) << 4;
    char* pb = (char*)&Ps[wq][0];
    char* pwW = pb + lr * 128;                      // + ((n*32+lg*8)^sw)
    const char* pr0 = pb + lr * 128 + ((lg * 16) ^ sw);
    const char* pr1 = pb + lr * 128 + ((64 + lg * 16) ^ sw);

    // Q fragments (B-op): Q[q = qb+lr][d = lg*8.. / 32+lg*8..]
    const __hip_bfloat16* Qrow = Qg + ((size_t)bh * 2048 + qb + lr) * 64 + lg * 8;
    short8 qf0 = *reinterpret_cast<const short8*>(Qrow);
    short8 qf1 = *reinterpret_cast<const short8*>(Qrow + 32);

    const f32x4 fz = {0.f, 0.f, 0.f, 0.f};
    f32x4 o[4];
#pragma unroll
    for (int n = 0; n < 4; n++) o[n] = fz;
    float m = -1e30f, lsum = 0.f;

    const int NT = qt + 1;
#pragma unroll 1
    for (int kt = 0; kt < NT; ++kt) {
        const char* kp = kL + (size_t)kt * 8192;
        const char* vp = vL + (size_t)kt * 128;

        // K fragment loads (8 x dwordx4, 16 coalesced 128B rows each)
        short8 k0[4], k1[4];
#pragma unroll
        for (int n = 0; n < 4; n++) {
            k0[n] = *reinterpret_cast<const short8*>(kp + n * 2048);
            k1[n] = *reinterpret_cast<const short8*>(kp + n * 2048 + 64);
        }

        // S^T = K Q^T
        f32x4 s[4];
#pragma unroll
        for (int n = 0; n < 4; n++) s[n] = fz;
        __builtin_amdgcn_s_setprio(1);
#pragma unroll
        for (int n = 0; n < 4; n++) {
            s[n] = __builtin_amdgcn_mfma_f32_16x16x32_bf16(k0[n], qf0, s[n], 0, 0, 0);
            s[n] = __builtin_amdgcn_mfma_f32_16x16x32_bf16(k1[n], qf1, s[n], 0, 0, 0);
        }
        __builtin_amdgcn_s_setprio(0);

        // V fragment loads issued now; latency hides under softmax
        short8 v0[4], v1[4];
#pragma unroll
        for (int n = 0; n < 4; n++) {
            v0[n] = *reinterpret_cast<const short8*>(vp + (size_t)n * 65536);
            v1[n] = *reinterpret_cast<const short8*>(vp + (size_t)n * 65536 + 64);
        }

        if (kt == NT - 1) {   // causal mask on the diagonal tile
            int q = qb + lr;
#pragma unroll
            for (int n = 0; n < 4; n++) {
                int kvb = kt * 64 + n * 16 + lg * 4;
#pragma unroll
                for (int r = 0; r < 4; r++)
                    if (kvb + r > q) s[n][r] = -1e30f;
            }
        }

        // row max (lane-local + 2 shuffles)
        float mx = fmaxf(fmaxf(fmaxf(s[0][0], s[0][1]), fmaxf(s[0][2], s[0][3])),
                         fmaxf(fmaxf(fmaxf(s[1][0], s[1][1]), fmaxf(s[1][2], s[1][3])),
                               fmaxf(fmaxf(fmaxf(s[2][0], s[2][1]), fmaxf(s[2][2], s[2][3])),
                                     fmaxf(fmaxf(s[3][0], s[3][1]), fmaxf(s[3][2], s[3][3])))));
        mx = fmaxf(mx, __shfl_xor(mx, 16));
        mx = fmaxf(mx, __shfl_xor(mx, 32));

        // defer-max: only rescale when some row grew by > 8*log2e
        if (!__all(mx - m <= 11.54f)) {
            float mnew = fmaxf(m, mx);
            float corr = __builtin_amdgcn_exp2f(m - mnew);
            m = mnew;
            lsum *= corr;
            float c0 = __shfl(corr, (lane & 48) | (lg * 4 + 0));
            float c1 = __shfl(corr, (lane & 48) | (lg * 4 + 1));
            float c2 = __shfl(corr, (lane & 48) | (lg * 4 + 2));
            float c3 = __shfl(corr, (lane & 48) | (lg * 4 + 3));
#pragma unroll
            for (int n = 0; n < 4; n++) {
                o[n][0] *= c0; o[n][1] *= c1; o[n][2] *= c2; o[n][3] *= c3;
            }
        }

        // P = 2^(S - m); lane-local partial row-sum
        float psum = 0.f;
#pragma unroll
        for (int n = 0; n < 4; n++) {
            float p0 = __builtin_amdgcn_exp2f(s[n][0] - m);
            float p1 = __builtin_amdgcn_exp2f(s[n][1] - m);
            float p2 = __builtin_amdgcn_exp2f(s[n][2] - m);
            float p3 = __builtin_amdgcn_exp2f(s[n][3] - m);
            s[n][0] = p0; s[n][1] = p1; s[n][2] = p2; s[n][3] = p3;
            psum += (p0 + p1) + (p2 + p3);
        }
        lsum += psum;

        // P -> per-wave LDS (A-fragment layout), no barrier needed
#pragma unroll
        for (int n = 0; n < 4; n++) {
            short4v pk;
            pk[0] = f2bf_bits(s[n][0]); pk[1] = f2bf_bits(s[n][1]);
            pk[2] = f2bf_bits(s[n][2]); pk[3] = f2bf_bits(s[n][3]);
            *reinterpret_cast<short4v*>(pwW + ((n * 32 + lg * 8) ^ sw)) = pk;
        }
        asm volatile("s_waitcnt lgkmcnt(0)" ::: "memory");
        short8 pa0 = *reinterpret_cast<const short8*>(pr0);
        short8 pa1 = *reinterpret_cast<const short8*>(pr1);

        // PV: O[q][d] += P V
        __builtin_amdgcn_s_setprio(1);
#pragma unroll
        for (int n = 0; n < 4; n++) {
            o[n] = __builtin_amdgcn_mfma_f32_16x16x32_bf16(pa0, v0[n], o[n], 0, 0, 0);
            o[n] = __builtin_amdgcn_mfma_f32_16x16x32_bf16(pa1, v1[n], o[n], 0, 0, 0);
        }
        __builtin_amdgcn_s_setprio(0);
    }

    // epilogue: finish deferred row-sum, normalize, store
    lsum += __shfl_xor(lsum, 16);
    lsum += __shfl_xor(lsum, 32);
    float l0 = __shfl(lsum, (lane & 48) | (lg * 4 + 0));
    float l1 = __shfl(lsum, (lane & 48) | (lg * 4 + 1));
    float l2 = __shfl(lsum, (lane & 48) | (lg * 4 + 2));
    float l3 = __shfl(lsum, (lane & 48) | (lg * 4 + 3));
    float inv[4] = {1.0f / l0, 1.0f / l1, 1.0f / l2, 1.0f / l3};
#pragma unroll
    for (int r = 0; r < 4; r++) {
        int tok = qb + lg * 4 + r;
        __hip_bfloat16* crow = ctx + ((size_t)(bb * 2048 + tok)) * 1024 + h * 64;
#pragma unroll
        for (int n = 0; n < 4; n++) crow[n * 16 + lr] = __float2bfloat16(o[n][r] * inv[r]);
    }
}

// ---------------- output projection GEMM (128x64 tile) ----------------
// 1D grid 512, XCD-chunked: per XCD 16(bx) x 4(by) -> ~3MB L2 working set.
__global__ __launch_bounds__(256) void gemm_out(const __hip_bfloat16* __restrict__ A,
                                                const __hip_bfloat16* __restrict__ B,
                                                const float* __restrict__ bias,
                                                float* __restrict__ out) {
    constexpr int K = 1024;
    __shared__ __hip_bfloat16 smem[2][128 * 32 + 64 * 32];
    const int tid = threadIdx.x;
    const int lane = tid & 63, wid = tid >> 6;
    const int wr = wid >> 1, wc = wid & 1;
    const int lr = lane & 15, lg = lane >> 4;

    const int bid = blockIdx.x;
    const int xcd = bid & 7, w = bid >> 3;     // w in [0,64)
    const int bx = w & 15;                     // [0,16)
    const int by = (xcd << 2) | (w >> 4);      // [0,32)
    const int m0 = by * 128;
    const int n0 = bx * 64;

    const f32x4 fz = {0.f, 0.f, 0.f, 0.f};
    f32x4 acc[4][2];
#pragma unroll
    for (int i = 0; i < 4; i++)
#pragma unroll
        for (int j = 0; j < 2; j++) acc[i][j] = fz;

    const char* Abase = (const char*)A + (size_t)m0 * K * 2;
    const char* Bbase = (const char*)B + (size_t)n0 * K * 2;

    auto stage = [&](int buf, int kt) {
        const int kb = kt * 64;
        char* sA = (char*)&smem[buf][0];
        char* sB = (char*)&smem[buf][128 * 32];
#pragma unroll
        for (int i = 0; i < 2; i++) {
            int o = i * 4096 + tid * 16;
            int row = o >> 6, cb = o & 63;
            __builtin_amdgcn_global_load_lds(GAS(Abase + (size_t)row * 2048 + kb + cb),
                                             LAS(sA + o), 16, 0, 0);
        }
        {
            int o = tid * 16;
            int row = o >> 6, cb = o & 63;
            __builtin_amdgcn_global_load_lds(GAS(Bbase + (size_t)row * 2048 + kb + cb),
                                             LAS(sB + o), 16, 0, 0);
        }
    };

    stage(0, 0);
    __syncthreads();
    int buf = 0;
    constexpr int NT = K / 32;
    for (int kt = 0; kt < NT; ++kt) {
        if (kt + 1 < NT) stage(buf ^ 1, kt + 1);
        const __hip_bfloat16* sA = &smem[buf][0];
        const __hip_bfloat16* sB = &smem[buf][128 * 32];
        short8 a[4], b[2];
#pragma unroll
        for (int i = 0; i < 4; i++)
            a[i] = *reinterpret_cast<const short8*>(sA + (wr * 64 + i * 16 + lr) * 32 + lg * 8);
#pragma unroll
        for (int j = 0; j < 2; j++)
            b[j] = *reinterpret_cast<const short8*>(sB + (wc * 32 + j * 16 + lr) * 32 + lg * 8);
#pragma unroll
        for (int i = 0; i < 4; i++)
#pragma unroll
            for (int j = 0; j < 2; j++)
                acc[i][j] = __builtin_amdgcn_mfma_f32_16x16x32_bf16(a[i], b[j], acc[i][j], 0, 0, 0);
        __syncthreads();
        buf ^= 1;
    }

#pragma unroll
    for (int j = 0; j < 2; j++) {
        int e = n0 + wc * 32 + j * 16 + lr;
        float bv = bias[e];
#pragma unroll
        for (int i = 0; i < 4; i++) {
            int mb = m0 + wr * 64 + i * 16 + lg * 4;
#pragma unroll
            for (int r = 0; r < 4; r++) {
                out[(size_t)(mb + r) * 1024 + e] = acc[i][j][r] + bv;
            }
        }
    }
}

extern "C" void kernel_launch(void* const* d_in, const int* in_sizes, int n_in,
                              void* d_out, int out_size, void* d_ws, size_t ws_size,
                              hipStream_t stream) {
    const float* x = (const float*)d_in[0];
    const float* w_in = (const float*)d_in[1];
    const float* b_in = (const float*)d_in[2];
    const float* w_out = (const float*)d_in[3];
    const float* b_out = (const float*)d_in[4];
    float* out = (float*)d_out;

    char* ws = (char*)d_ws;
    __hip_bfloat16* xbf  = (__hip_bfloat16*)(ws);
    __hip_bfloat16* wbf  = (__hip_bfloat16*)(ws + (8ull << 20));
    __hip_bfloat16* owbf = (__hip_bfloat16*)(ws + (14ull << 20));
    __hip_bfloat16* Qb   = (__hip_bfloat16*)(ws + (16ull << 20));
    __hip_bfloat16* Kb   = (__hip_bfloat16*)(ws + (24ull << 20));
    __hip_bfloat16* Vt   = (__hip_bfloat16*)(ws + (40ull << 20));
    __hip_bfloat16* ctxb = (__hip_bfloat16*)(ws + (48ull << 20));

    cvt_all<<<4096, 256, 0, stream>>>(x, w_in, w_out, (short*)xbf, (short*)wbf, (short*)owbf);
    gemm_qkv<<<768, 256, 0, stream>>>(xbf, wbf, b_in, Qb, Kb, Vt);
    attn<<<1024, 256, 0, stream>>>(Qb, Kb, Vt, ctxb);
    gemm_out<<<512, 256, 0, stream>>>(ctxb, owbf, b_out, out);
}